// Round 18
// baseline (137.154 us; speedup 1.0000x reference)
//
#include <hip/hip_runtime.h>

static constexpr int SD = 21, HD = 64, LT = 14;
static constexpr int NFRAG = 36;     // 16x16x16 B-fragments, ws[fid*128 + lane*2 + j]

typedef _Float16       f16x4  __attribute__((ext_vector_type(4)));
typedef float          f32x4  __attribute__((ext_vector_type(4)));
typedef unsigned       u32x2v __attribute__((ext_vector_type(2)));
typedef unsigned short u16x4v __attribute__((ext_vector_type(4)));
typedef __fp16         pk2    __attribute__((ext_vector_type(2)));

__device__ __forceinline__ float frcp(float x){ return __builtin_amdgcn_rcpf(x); }
__device__ __forceinline__ float frsq(float x){ return __builtin_amdgcn_rsqf(x); }

__device__ __forceinline__ unsigned packrtz(float a, float b){
    pk2 h = __builtin_amdgcn_cvt_pkrtz(a, b);
    union { pk2 h; unsigned u; } u; u.h = h; return u.u;
}
__device__ __forceinline__ unsigned short f16bits(float v){
    _Float16 h = (_Float16)v;
    union { _Float16 h; unsigned short s; } u; u.h = h; return u.s;
}
__device__ __forceinline__ float ftanh(float x){
    x = fminf(15.0f, fmaxf(-15.0f, x));
    float e = __expf(2.0f * x);
    return (e - 1.0f) * frcp(e + 1.0f);
}
template<int NN>
__device__ __forceinline__ void softmax_scale(float (&v)[NN], float gate){
    float mx = v[0];
#pragma unroll
    for (int j = 1; j < NN; ++j) mx = fmaxf(mx, v[j]);
    float s = 0.0f;
#pragma unroll
    for (int j = 0; j < NN; ++j){ v[j] = __expf(v[j] - mx); s += v[j]; }
    float r = frcp(s) * gate;
#pragma unroll
    for (int j = 0; j < NN; ++j) v[j] *= r;
}

union Frag2 { u32x2v u2; unsigned u[2]; f16x4 f; };
union FragH { u16x4v uh; f16x4 f; };

__device__ __forceinline__ f32x4 mfma16(f16x4 a, f16x4 b, f32x4 c){
    return __builtin_amdgcn_mfma_f32_16x16x16f16(a, b, c, 0, 0, 0);
}

// ---- B-fragment pack: layout col=l&15, k=4*(l>>4)+r (HW-verified R12/R13/R14) ----
// fid: 0-7 enc1 | 8-23 enc2 | 24-27 enc3 | 28-31 dec1 | 32-35 dec2
__global__ void pack_bfrags(const float* __restrict__ W1, const float* __restrict__ W2,
                            const float* __restrict__ W3, const float* __restrict__ Wd1,
                            const float* __restrict__ Wd2, unsigned* __restrict__ ws)
{
    int t = blockIdx.x * blockDim.x + threadIdx.x;
    if (t >= NFRAG * 64) return;
    int fid = t >> 6, lane = t & 63;
    int g = lane >> 4, c = lane & 15;
    const float* W; int ks16, ct, K, Ncol, ld;
    if (fid < 8)       { W = W1;  ks16 = fid >> 2;    ct = fid & 3;  K = 21; Ncol = 64; ld = 64; }
    else if (fid < 24) { int e = fid - 8;
                         W = W2;  ks16 = e >> 2;      ct = e & 3;    K = 64; Ncol = 64; ld = 64; }
    else if (fid < 28) { W = W3;  ks16 = fid - 24;    ct = 0;        K = 64; Ncol = 14; ld = 14; }
    else if (fid < 32) { W = Wd1; ks16 = 0;           ct = fid - 28; K = 14; Ncol = 64; ld = 64; }
    else               { W = Wd2; ks16 = fid - 32;    ct = 0;        K = 64; Ncol = 8;  ld = 8;  }
    int col = ct*16 + c;
#pragma unroll
    for (int j = 0; j < 2; ++j) {
        int k0 = ks16*16 + g*4 + 2*j;
        float a = (k0     < K && col < Ncol) ? W[k0*ld + col]     : 0.0f;
        float b = (k0 + 1 < K && col < Ncol) ? W[(k0+1)*ld + col] : 0.0f;
        ws[fid*128 + lane*2 + j] = packrtz(a, b);
    }
}

__global__ __launch_bounds__(256) void statenet_mfma5(
    const float* __restrict__ state,
    const unsigned* __restrict__ pw,
    const float* __restrict__ b1,
    const float* __restrict__ lng, const float* __restrict__ lnb,
    const float* __restrict__ b2,  const float* __restrict__ b3,
    const float* __restrict__ bd1, const float* __restrict__ bd2,
    const float* __restrict__ Wm,  const float* __restrict__ bm,
    const float* __restrict__ Wh,  const float* __restrict__ bh,
    const float* __restrict__ Wc,  const float* __restrict__ bc,
    const float* __restrict__ psm, const float* __restrict__ psh,
    const float* __restrict__ psc,
    float* __restrict__ out, int N)
{
    // 64 rows per wave. OVERLAY (R16-verified discipline): one 9216 B region per
    // wave serves as BOTH at[64][36] u32 and hb[64][72] f16 — never live at once;
    // all A-operands are read to REGISTERS before the region changes role, and
    // role transitions are barrier-separated.
    __shared__ __align__(16) unsigned s_buf[4*2304];     // 36864 B/block

    const int tid = threadIdx.x;
    const int w  = tid >> 6, l = tid & 63;
    const int cl = l & 15,  g = l >> 4;
    const long long rowbase = (long long)blockIdx.x * 256 + w * 64;

    unsigned*       at = s_buf + w * 2304;
    unsigned short* hb = reinterpret_cast<unsigned short*>(s_buf) + w * 4608;

    // ============ T1: heads + attended staging — ALL 64 lanes, 1 row each ============
    {
        const long long row = rowbase + l;
        float ns[SD];
        {
            const float* p = state + row * SD;
#pragma unroll
            for (int k = 0; k < SD; ++k) ns[k] = p[k];
        }
        ns[0]  *= (1.0f / 3.0f);
        ns[1]  *= (1.0f / 3.0f);
        ns[17] *= 0.5f;
        ns[18] *= 0.25f;
        ns[19]  = fminf(fmaxf(ns[19], 0.0f), 2.0f) * 0.5f;

        float m[13], hv[6], cv[4];
#pragma unroll
        for (int j = 0; j < 13; ++j) m[j]  = bm[j];
#pragma unroll
        for (int j = 0; j < 6;  ++j) hv[j] = bh[j];
#pragma unroll
        for (int j = 0; j < 4;  ++j) cv[j] = bc[j];
#pragma unroll
        for (int k = 0; k < SD; ++k) {
            float x = ns[k];
#pragma unroll
            for (int j = 0; j < 13; ++j) m[j]  = fmaf(x, Wm[k * 13 + j], m[j]);
#pragma unroll
            for (int j = 0; j < 6;  ++j) hv[j] = fmaf(x, Wh[k * 6 + j], hv[j]);
#pragma unroll
            for (int j = 0; j < 4;  ++j) cv[j] = fmaf(x, Wc[k * 4 + j], cv[j]);
        }
        const float gm = 2.0f * frcp(1.0f + __expf(-psm[0]));
        const float gh = 2.0f * frcp(1.0f + __expf(-psh[0]));
        const float gc = 2.0f * frcp(1.0f + __expf(-psc[0]));
        softmax_scale<13>(m,  gm);
        softmax_scale<6 >(hv, gh);
        softmax_scale<4 >(cv, gc);

        {
            float* pm = out + (long long)22 * N + row * 13;
#pragma unroll
            for (int j = 0; j < 13; ++j) pm[j] = m[j];
            float* ph = out + (long long)35 * N + row * 6;
#pragma unroll
            for (int j = 0; j < 3; ++j)
                reinterpret_cast<float2*>(ph)[j] = make_float2(hv[2*j], hv[2*j+1]);
            float* pc = out + (long long)41 * N + row * 4;
            reinterpret_cast<float4*>(pc)[0] = make_float4(cv[0], cv[1], cv[2], cv[3]);
        }

        constexpr int EIDX[SD] = {0,1,2,3,4,4,5,5,5,6,6,6,7,7,8,9,9,10,10,11,12};
        float atv[SD];
#pragma unroll
        for (int k = 0; k < SD; ++k) atv[k] = ns[k] * m[EIDX[k]];
        const int base = l * 36;
#pragma unroll
        for (int kk = 0; kk < 10; ++kk) at[base + kk] = packrtz(atv[2*kk], atv[2*kk+1]);
        at[base + 10] = packrtz(atv[20], 0.0f);
#pragma unroll
        for (int kk = 11; kk < 16; ++kk) at[base + kk] = 0u;
    }
    __syncthreads();                                   // B1: at ready

    // ============ MFMA phase: 4 M-tiles, processed in 2 half-M passes ============
    float b1c[4], b2c[4], bd1c[4], lgc[4], lbc[4];
#pragma unroll
    for (int t2 = 0; t2 < 4; ++t2) {
        int c2 = cl + 16*t2;
        b1c[t2] = b1[c2];  b2c[t2] = b2[c2];  bd1c[t2] = bd1[c2];
        lgc[t2] = lng[c2]; lbc[t2] = lnb[c2];
    }
    const float b3c  = (cl < 14) ? b3[cl]  : 0.0f;
    const float bd2c = (cl < 8)  ? bd2[cl] : 0.0f;

    const u32x2v* BF2 = reinterpret_cast<const u32x2v*>(pw);
    const f32x4 vzero = {0.0f, 0.0f, 0.0f, 0.0f};

    // ---- enc1: read ALL at A-frags -> regs (16 VGPR), then region may flip ----
    Frag2 aA[4][2];
#pragma unroll
    for (int M = 0; M < 4; ++M)
#pragma unroll
        for (int ks = 0; ks < 2; ++ks)
            aA[M][ks].u2 = *reinterpret_cast<const u32x2v*>(&at[(M*16 + cl)*36 + ks*8 + 2*g]);
    __syncthreads();                                   // B2: at dead -> hb

#pragma unroll
    for (int mh = 0; mh < 2; ++mh) {
        f32x4 acc[2][4];
#pragma unroll
        for (int m2 = 0; m2 < 2; ++m2)
#pragma unroll
            for (int ct = 0; ct < 4; ++ct) acc[m2][ct] = vzero;
#pragma unroll
        for (int ct = 0; ct < 4; ++ct)
#pragma unroll
            for (int ks = 0; ks < 2; ++ks) {
                Frag2 bf; bf.u2 = BF2[(ks*4 + ct)*64 + l];
#pragma unroll
                for (int m2 = 0; m2 < 2; ++m2)
                    acc[m2][ct] = mfma16(aA[mh*2 + m2][ks].f, bf.f, acc[m2][ct]);
            }
        // LN + tanh -> hb (VERIFIED epilogue)
#pragma unroll
        for (int m2 = 0; m2 < 2; ++m2) {
            float s[4], ss[4];
#pragma unroll
            for (int q = 0; q < 4; ++q) {
                float v0 = acc[m2][0][q] + b1c[0], v1 = acc[m2][1][q] + b1c[1];
                float v2 = acc[m2][2][q] + b1c[2], v3 = acc[m2][3][q] + b1c[3];
                acc[m2][0][q] = v0; acc[m2][1][q] = v1; acc[m2][2][q] = v2; acc[m2][3][q] = v3;
                s[q]  = v0 + v1 + v2 + v3;
                ss[q] = v0*v0 + v1*v1 + v2*v2 + v3*v3;
            }
#pragma unroll
            for (int q = 0; q < 4; ++q) {
#pragma unroll
                for (int d = 1; d < 16; d <<= 1) {
                    s[q]  += __shfl_xor(s[q],  d, 16);
                    ss[q] += __shfl_xor(ss[q], d, 16);
                }
            }
#pragma unroll
            for (int q = 0; q < 4; ++q) {
                float mu   = s[q] * (1.0f/64.0f);
                float var  = ss[q] * (1.0f/64.0f) - mu*mu;
                float istd = frsq(var + 1e-5f);
                int r = (mh*2 + m2)*16 + g*4 + q;
#pragma unroll
                for (int t2 = 0; t2 < 4; ++t2) {
                    float v = ftanh(fmaf((acc[m2][t2][q] - mu) * istd, lgc[t2], lbc[t2]));
                    hb[r*72 + cl + 16*t2] = f16bits(v);
                }
            }
        }
    }
    __syncthreads();                                   // B3: hb(h1) ready

    // ---- enc2: read ALL h1 A-frags -> regs (32 VGPR) ----
    FragH ah[4][4];
#pragma unroll
    for (int M = 0; M < 4; ++M)
#pragma unroll
        for (int ks = 0; ks < 4; ++ks)
            ah[M][ks].uh = *reinterpret_cast<const u16x4v*>(&hb[(M*16 + cl)*72 + ks*16 + 4*g]);
    __syncthreads();                                   // B4: h1 dead
#pragma unroll
    for (int mh = 0; mh < 2; ++mh) {
        f32x4 a2[2][4];
#pragma unroll
        for (int m2 = 0; m2 < 2; ++m2)
#pragma unroll
            for (int ct = 0; ct < 4; ++ct) a2[m2][ct] = vzero;
#pragma unroll
        for (int ct = 0; ct < 4; ++ct)
#pragma unroll
            for (int ks = 0; ks < 4; ++ks) {
                Frag2 bf; bf.u2 = BF2[(8 + ks*4 + ct)*64 + l];
#pragma unroll
                for (int m2 = 0; m2 < 2; ++m2)
                    a2[m2][ct] = mfma16(ah[mh*2 + m2][ks].f, bf.f, a2[m2][ct]);
            }
#pragma unroll
        for (int m2 = 0; m2 < 2; ++m2)
#pragma unroll
            for (int q = 0; q < 4; ++q) {
                int r = (mh*2 + m2)*16 + g*4 + q;
#pragma unroll
                for (int t2 = 0; t2 < 4; ++t2)
                    hb[r*72 + cl + 16*t2] = f16bits(fmaxf(a2[m2][t2][q] + b2c[t2], 0.0f));
            }
    }
    __syncthreads();                                   // B5: hb(h2) ready

    // ---- enc3: read ALL h2 A-frags -> regs ----
#pragma unroll
    for (int M = 0; M < 4; ++M)
#pragma unroll
        for (int ks = 0; ks < 4; ++ks)
            ah[M][ks].uh = *reinterpret_cast<const u16x4v*>(&hb[(M*16 + cl)*72 + ks*16 + 4*g]);
    __syncthreads();                                   // B6: h2 dead -> at(latent)
#pragma unroll
    for (int M = 0; M < 4; ++M) {
        f32x4 a3 = vzero;
#pragma unroll
        for (int ks = 0; ks < 4; ++ks) {
            Frag2 bf; bf.u2 = BF2[(24 + ks)*64 + l];
            a3 = mfma16(ah[M][ks].f, bf.f, a3);
        }
#pragma unroll
        for (int q = 0; q < 4; ++q) {
            float lv = a3[q] + b3c;                 // pad cols 14/15 = 0
            int r = M*16 + g*4 + q;
            if (cl < 14)
                out[(long long)8 * N + (rowbase + r) * 14 + cl] = lv;
            // pair with column-partner lane (cl^1) -> f16-pair staging (VERIFIED R16)
            float pv = __shfl_xor(lv, 1);
            if ((cl & 1) == 0)
                at[r*36 + (cl >> 1)] = packrtz(lv, pv);
        }
    }
    __syncthreads();                                   // B7: at(latent) ready

    // ---- dec1: read ALL latent A-frags -> regs (8 VGPR) ----
    Frag2 aD[4];
#pragma unroll
    for (int M = 0; M < 4; ++M)
        aD[M].u2 = *reinterpret_cast<const u32x2v*>(&at[(M*16 + cl)*36 + 2*g]);
    __syncthreads();                                   // B8: latent dead -> hb
#pragma unroll
    for (int mh = 0; mh < 2; ++mh) {
        f32x4 ad[2][4];
#pragma unroll
        for (int m2 = 0; m2 < 2; ++m2)
#pragma unroll
            for (int ct = 0; ct < 4; ++ct) ad[m2][ct] = vzero;
#pragma unroll
        for (int ct = 0; ct < 4; ++ct) {
            Frag2 bf; bf.u2 = BF2[(28 + ct)*64 + l];
#pragma unroll
            for (int m2 = 0; m2 < 2; ++m2)
                ad[m2][ct] = mfma16(aD[mh*2 + m2].f, bf.f, ad[m2][ct]);
        }
#pragma unroll
        for (int m2 = 0; m2 < 2; ++m2)
#pragma unroll
            for (int q = 0; q < 4; ++q) {
                int r = (mh*2 + m2)*16 + g*4 + q;
#pragma unroll
                for (int t2 = 0; t2 < 4; ++t2)
                    hb[r*72 + cl + 16*t2] = f16bits(fmaxf(ad[m2][t2][q] + bd1c[t2], 0.0f));
            }
    }
    __syncthreads();                                   // B9: hb(d1) ready

    // ---- dec2 (VERIFIED R14) -> tanh -> corrections ----
#pragma unroll
    for (int M = 0; M < 4; ++M)
#pragma unroll
        for (int ks = 0; ks < 4; ++ks)
            ah[M][ks].uh = *reinterpret_cast<const u16x4v*>(&hb[(M*16 + cl)*72 + ks*16 + 4*g]);
#pragma unroll
    for (int M = 0; M < 4; ++M) {
        f32x4 a5 = vzero;
#pragma unroll
        for (int ks = 0; ks < 4; ++ks) {
            Frag2 bf; bf.u2 = BF2[(32 + ks)*64 + l];
            a5 = mfma16(ah[M][ks].f, bf.f, a5);
        }
#pragma unroll
        for (int q = 0; q < 4; ++q) {
            if (cl < 8)
                out[(rowbase + M*16 + g*4 + q) * 8 + cl] = ftanh(a5[q] + bd2c);
        }
    }
}

extern "C" void kernel_launch(void* const* d_in, const int* in_sizes, int n_in,
                              void* d_out, int out_size, void* d_ws, size_t ws_size,
                              hipStream_t stream)
{
    const float* state = (const float*)d_in[0];
    const float* W1   = (const float*)d_in[1];
    const float* b1   = (const float*)d_in[2];
    const float* lng  = (const float*)d_in[3];
    const float* lnb  = (const float*)d_in[4];
    const float* W2   = (const float*)d_in[5];
    const float* b2   = (const float*)d_in[6];
    const float* W3   = (const float*)d_in[7];
    const float* b3   = (const float*)d_in[8];
    const float* Wd1  = (const float*)d_in[9];
    const float* bd1  = (const float*)d_in[10];
    const float* Wd2  = (const float*)d_in[11];
    const float* bd2  = (const float*)d_in[12];
    const float* Wm   = (const float*)d_in[13];
    const float* bm   = (const float*)d_in[14];
    const float* Wh   = (const float*)d_in[15];
    const float* bh   = (const float*)d_in[16];
    const float* Wc   = (const float*)d_in[17];
    const float* bc   = (const float*)d_in[18];
    const float* psm  = (const float*)d_in[19];
    const float* psh  = (const float*)d_in[20];
    const float* psc  = (const float*)d_in[21];

    unsigned* pw = (unsigned*)d_ws;

    hipLaunchKernelGGL(pack_bfrags, dim3((NFRAG*64 + 255)/256), dim3(256), 0, stream,
                       W1, W2, W3, Wd1, Wd2, pw);

    const int N = in_sizes[0] / SD;              // 1048576
    hipLaunchKernelGGL(statenet_mfma5, dim3(N / 256), dim3(256), 0, stream,
                       state, pw, b1, lng, lnb, b2, b3, bd1, bd2,
                       Wm, bm, Wh, bh, Wc, bc, psm, psh, psc,
                       (float*)d_out, N);
}

// Round 19
// 128.592 us; speedup vs baseline: 1.0666x; 1.0666x over previous
//
#include <hip/hip_runtime.h>

static constexpr int SD = 21, HD = 64, LT = 14;
static constexpr int NFRAG = 40;     // 36 MLP frags + 4 head frags (fid 36-39)

typedef _Float16       f16x4  __attribute__((ext_vector_type(4)));
typedef float          f32x4  __attribute__((ext_vector_type(4)));
typedef unsigned       u32x2v __attribute__((ext_vector_type(2)));
typedef unsigned short u16x4v __attribute__((ext_vector_type(4)));
typedef __fp16         pk2    __attribute__((ext_vector_type(2)));

__device__ __forceinline__ float frcp(float x){ return __builtin_amdgcn_rcpf(x); }
__device__ __forceinline__ float frsq(float x){ return __builtin_amdgcn_rsqf(x); }

__device__ __forceinline__ unsigned packrtz(float a, float b){
    pk2 h = __builtin_amdgcn_cvt_pkrtz(a, b);
    union { pk2 h; unsigned u; } u; u.h = h; return u.u;
}
__device__ __forceinline__ unsigned short f16bits(float v){
    _Float16 h = (_Float16)v;
    union { _Float16 h; unsigned short s; } u; u.h = h; return u.s;
}
__device__ __forceinline__ float ftanh(float x){
    x = fminf(15.0f, fmaxf(-15.0f, x));
    float e = __expf(2.0f * x);
    return (e - 1.0f) * frcp(e + 1.0f);
}
template<int NN>
__device__ __forceinline__ void softmax_scale(float (&v)[NN], float gate){
    float mx = v[0];
#pragma unroll
    for (int j = 1; j < NN; ++j) mx = fmaxf(mx, v[j]);
    float s = 0.0f;
#pragma unroll
    for (int j = 0; j < NN; ++j){ v[j] = __expf(v[j] - mx); s += v[j]; }
    float r = frcp(s) * gate;
#pragma unroll
    for (int j = 0; j < NN; ++j) v[j] *= r;
}

union Frag2 { u32x2v u2; unsigned u[2]; f16x4 f; };
union FragH { u16x4v uh; f16x4 f; };

__device__ __forceinline__ f32x4 mfma16(f16x4 a, f16x4 b, f32x4 c){
    return __builtin_amdgcn_mfma_f32_16x16x16f16(a, b, c, 0, 0, 0);
}

// heads concat weight: col j of [Wm | Wh | Wc] (21 x 23)
__device__ __forceinline__ float headsW(const float* Wm, const float* Wh,
                                        const float* Wc, int k, int j){
    if (j < 13) return Wm[k*13 + j];
    if (j < 19) return Wh[k*6 + (j - 13)];
    if (j < 23) return Wc[k*4 + (j - 19)];
    return 0.0f;
}

// ---- B-fragment pack: layout col=l&15, k=4*(l>>4)+r (HW-verified R12/R13/R14) ----
// fid: 0-7 enc1 | 8-23 enc2 | 24-27 enc3 | 28-31 dec1 | 32-35 dec2 | 36-39 heads
__global__ void pack_bfrags(const float* __restrict__ W1, const float* __restrict__ W2,
                            const float* __restrict__ W3, const float* __restrict__ Wd1,
                            const float* __restrict__ Wd2,
                            const float* __restrict__ Wm, const float* __restrict__ Wh,
                            const float* __restrict__ Wc, unsigned* __restrict__ ws)
{
    int t = blockIdx.x * blockDim.x + threadIdx.x;
    if (t >= NFRAG * 64) return;
    int fid = t >> 6, lane = t & 63;
    int g = lane >> 4, c = lane & 15;

    if (fid >= 36) {                 // heads: [Wm|Wh|Wc] 21x23, K pad 32, col pad 32
        int e = fid - 36, ks16 = e >> 1, ct = e & 1;
        int col = ct*16 + c;
#pragma unroll
        for (int j = 0; j < 2; ++j) {
            int k0 = ks16*16 + g*4 + 2*j;
            float a = (k0     < SD && col < 23) ? headsW(Wm, Wh, Wc, k0,   col) : 0.0f;
            float b = (k0 + 1 < SD && col < 23) ? headsW(Wm, Wh, Wc, k0+1, col) : 0.0f;
            ws[fid*128 + lane*2 + j] = packrtz(a, b);
        }
        return;
    }

    const float* W; int ks16, ct, K, Ncol, ld;
    if (fid < 8)       { W = W1;  ks16 = fid >> 2;    ct = fid & 3;  K = 21; Ncol = 64; ld = 64; }
    else if (fid < 24) { int e = fid - 8;
                         W = W2;  ks16 = e >> 2;      ct = e & 3;    K = 64; Ncol = 64; ld = 64; }
    else if (fid < 28) { W = W3;  ks16 = fid - 24;    ct = 0;        K = 64; Ncol = 14; ld = 14; }
    else if (fid < 32) { W = Wd1; ks16 = 0;           ct = fid - 28; K = 14; Ncol = 64; ld = 64; }
    else               { W = Wd2; ks16 = fid - 32;    ct = 0;        K = 64; Ncol = 8;  ld = 8;  }
    int col = ct*16 + c;
#pragma unroll
    for (int j = 0; j < 2; ++j) {
        int k0 = ks16*16 + g*4 + 2*j;
        float a = (k0     < K && col < Ncol) ? W[k0*ld + col]     : 0.0f;
        float b = (k0 + 1 < K && col < Ncol) ? W[(k0+1)*ld + col] : 0.0f;
        ws[fid*128 + lane*2 + j] = packrtz(a, b);
    }
}

__global__ __launch_bounds__(256) void statenet_mfma6(
    const float* __restrict__ state,
    const unsigned* __restrict__ pw,
    const float* __restrict__ b1,
    const float* __restrict__ lng, const float* __restrict__ lnb,
    const float* __restrict__ b2,  const float* __restrict__ b3,
    const float* __restrict__ bd1, const float* __restrict__ bd2,
    const float* __restrict__ bm,  const float* __restrict__ bh,
    const float* __restrict__ bc,
    const float* __restrict__ psm, const float* __restrict__ psh,
    const float* __restrict__ psc,
    float* __restrict__ out, int N)
{
    // R17-verified overlay: at[32][36] u32  <->  hb[32][72] f16 per wave.
    __shared__ __align__(16) unsigned s_buf[4*1152];   // 18432 B
    // logits: [32][26] f32 per wave (stride 26 -> conflict-free float2)
    __shared__ __align__(16) float    s_lg[4*832];     // 13312 B

    const int tid = threadIdx.x;
    const int w  = tid >> 6, l = tid & 63;
    const int cl = l & 15,  g = l >> 4;
    const long long rowbase = (long long)blockIdx.x * 128 + w * 32;

    unsigned*       at  = s_buf + w * 1152;
    unsigned short* hb  = reinterpret_cast<unsigned short*>(s_buf) + w * 2304;
    float*          slg = s_lg + w * 832;

    // per-lane head-bias for logit columns (ct0 col=cl, ct1 col=16+cl)
    const float bc0 = (cl < 13) ? bm[cl] : bh[cl - 13];
    const float bc1 = (cl < 3) ? bh[cl + 3] : ((cl < 7) ? bc[cl - 3] : 0.0f);

    // ============ T1-A: load + normalize + stage ns (lanes 0..31) ============
    float ns[SD];
    if (l < 32) {
        const long long row = rowbase + l;
        {
            const float* p = state + row * SD;
#pragma unroll
            for (int k = 0; k < SD; ++k) ns[k] = p[k];
        }
        ns[0]  *= (1.0f / 3.0f);
        ns[1]  *= (1.0f / 3.0f);
        ns[17] *= 0.5f;
        ns[18] *= 0.25f;
        ns[19]  = fminf(fmaxf(ns[19], 0.0f), 2.0f) * 0.5f;

        const int base = l * 36;
#pragma unroll
        for (int kk = 0; kk < 10; ++kk) at[base + kk] = packrtz(ns[2*kk], ns[2*kk+1]);
        at[base + 10] = packrtz(ns[20], 0.0f);
#pragma unroll
        for (int kk = 11; kk < 16; ++kk) at[base + kk] = 0u;
    }
    __syncthreads();                                   // B1: at(ns) ready

    // ============ heads MFMA: logits = ns @ [Wm|Wh|Wc] ============
    const u32x2v* BF2 = reinterpret_cast<const u32x2v*>(pw);
    const f32x4 vzero = {0.0f, 0.0f, 0.0f, 0.0f};
    {
        Frag2 aN[2][2];
#pragma unroll
        for (int m2 = 0; m2 < 2; ++m2)
#pragma unroll
            for (int ks = 0; ks < 2; ++ks)
                aN[m2][ks].u2 = *reinterpret_cast<const u32x2v*>(&at[(m2*16 + cl)*36 + ks*8 + 2*g]);
        f32x4 hl[2][2];
#pragma unroll
        for (int m2 = 0; m2 < 2; ++m2)
#pragma unroll
            for (int ct = 0; ct < 2; ++ct) hl[m2][ct] = vzero;
#pragma unroll
        for (int ct = 0; ct < 2; ++ct)
#pragma unroll
            for (int ks = 0; ks < 2; ++ks) {
                Frag2 bf; bf.u2 = BF2[(36 + ks*2 + ct)*64 + l];
#pragma unroll
                for (int m2 = 0; m2 < 2; ++m2)
                    hl[m2][ct] = mfma16(aN[m2][ks].f, bf.f, hl[m2][ct]);
            }
        // scatter logits + bias to s_lg (C-layout coords: row=m2*16+g*4+q, col)
#pragma unroll
        for (int m2 = 0; m2 < 2; ++m2)
#pragma unroll
            for (int q = 0; q < 4; ++q) {
                int r = m2*16 + g*4 + q;
                slg[r*26 + cl] = hl[m2][0][q] + bc0;
                if (cl < 8) slg[r*26 + 16 + cl] = hl[m2][1][q] + bc1;
            }
    }
    __syncthreads();                                   // B2: logits ready (aN reads done)

    // ============ T1-B: softmax + head stores + attended (lanes 0..31) ============
    if (l < 32) {
        const long long row = rowbase + l;
        float lg[24];
#pragma unroll
        for (int i = 0; i < 12; ++i) {
            float2 v = *reinterpret_cast<const float2*>(&slg[l*26 + 2*i]);
            lg[2*i] = v.x; lg[2*i+1] = v.y;
        }
        float m[13], hv[6], cv[4];
#pragma unroll
        for (int j = 0; j < 13; ++j) m[j]  = lg[j];
#pragma unroll
        for (int j = 0; j < 6;  ++j) hv[j] = lg[13 + j];
#pragma unroll
        for (int j = 0; j < 4;  ++j) cv[j] = lg[19 + j];

        const float gm = 2.0f * frcp(1.0f + __expf(-psm[0]));
        const float gh = 2.0f * frcp(1.0f + __expf(-psh[0]));
        const float gc = 2.0f * frcp(1.0f + __expf(-psc[0]));
        softmax_scale<13>(m,  gm);
        softmax_scale<6 >(hv, gh);
        softmax_scale<4 >(cv, gc);

        {
            float* pm = out + (long long)22 * N + row * 13;
#pragma unroll
            for (int j = 0; j < 13; ++j) pm[j] = m[j];
            float* ph = out + (long long)35 * N + row * 6;
#pragma unroll
            for (int j = 0; j < 3; ++j)
                reinterpret_cast<float2*>(ph)[j] = make_float2(hv[2*j], hv[2*j+1]);
            float* pc = out + (long long)41 * N + row * 4;
            reinterpret_cast<float4*>(pc)[0] = make_float4(cv[0], cv[1], cv[2], cv[3]);
        }

        constexpr int EIDX[SD] = {0,1,2,3,4,4,5,5,5,6,6,6,7,7,8,9,9,10,10,11,12};
        float atv[SD];
#pragma unroll
        for (int k = 0; k < SD; ++k) atv[k] = ns[k] * m[EIDX[k]];
        const int base = l * 36;
#pragma unroll
        for (int kk = 0; kk < 10; ++kk) at[base + kk] = packrtz(atv[2*kk], atv[2*kk+1]);
        at[base + 10] = packrtz(atv[20], 0.0f);
        // pads 11..15 still zero from T1-A
    }
    __syncthreads();                                   // B3: at(attended) ready

    // ============ MFMA chain (R17-verified, unchanged) ============
    float b1c[4], b2c[4], bd1c[4], lgc[4], lbc[4];
#pragma unroll
    for (int t2 = 0; t2 < 4; ++t2) {
        int c2 = cl + 16*t2;
        b1c[t2] = b1[c2];  b2c[t2] = b2[c2];  bd1c[t2] = bd1[c2];
        lgc[t2] = lng[c2]; lbc[t2] = lnb[c2];
    }
    const float b3c  = (cl < 14) ? b3[cl]  : 0.0f;
    const float bd2c = (cl < 8)  ? bd2[cl] : 0.0f;

    // ---- enc1: read at -> regs ----
    Frag2 aA[2][2];
#pragma unroll
    for (int m2 = 0; m2 < 2; ++m2)
#pragma unroll
        for (int ks = 0; ks < 2; ++ks)
            aA[m2][ks].u2 = *reinterpret_cast<const u32x2v*>(&at[(m2*16 + cl)*36 + ks*8 + 2*g]);
    __syncthreads();                                   // B4: at dead -> hb

    f32x4 acc[2][4];
#pragma unroll
    for (int m2 = 0; m2 < 2; ++m2)
#pragma unroll
        for (int ct = 0; ct < 4; ++ct) acc[m2][ct] = vzero;
#pragma unroll
    for (int ct = 0; ct < 4; ++ct)
#pragma unroll
        for (int ks = 0; ks < 2; ++ks) {
            Frag2 bf; bf.u2 = BF2[(ks*4 + ct)*64 + l];
#pragma unroll
            for (int m2 = 0; m2 < 2; ++m2)
                acc[m2][ct] = mfma16(aA[m2][ks].f, bf.f, acc[m2][ct]);
        }
#pragma unroll
    for (int m2 = 0; m2 < 2; ++m2) {
        float s[4], ss[4];
#pragma unroll
        for (int q = 0; q < 4; ++q) {
            float v0 = acc[m2][0][q] + b1c[0], v1 = acc[m2][1][q] + b1c[1];
            float v2 = acc[m2][2][q] + b1c[2], v3 = acc[m2][3][q] + b1c[3];
            acc[m2][0][q] = v0; acc[m2][1][q] = v1; acc[m2][2][q] = v2; acc[m2][3][q] = v3;
            s[q]  = v0 + v1 + v2 + v3;
            ss[q] = v0*v0 + v1*v1 + v2*v2 + v3*v3;
        }
#pragma unroll
        for (int q = 0; q < 4; ++q) {
#pragma unroll
            for (int d = 1; d < 16; d <<= 1) {
                s[q]  += __shfl_xor(s[q],  d, 16);
                ss[q] += __shfl_xor(ss[q], d, 16);
            }
        }
#pragma unroll
        for (int q = 0; q < 4; ++q) {
            float mu   = s[q] * (1.0f/64.0f);
            float var  = ss[q] * (1.0f/64.0f) - mu*mu;
            float istd = frsq(var + 1e-5f);
            int r = m2*16 + g*4 + q;
#pragma unroll
            for (int t2 = 0; t2 < 4; ++t2) {
                float v = ftanh(fmaf((acc[m2][t2][q] - mu) * istd, lgc[t2], lbc[t2]));
                hb[r*72 + cl + 16*t2] = f16bits(v);
            }
        }
    }
    __syncthreads();                                   // B5: hb(h1) ready

    // ---- enc2 ----
    FragH ah[2][4];
#pragma unroll
    for (int m2 = 0; m2 < 2; ++m2)
#pragma unroll
        for (int ks = 0; ks < 4; ++ks)
            ah[m2][ks].uh = *reinterpret_cast<const u16x4v*>(&hb[(m2*16 + cl)*72 + ks*16 + 4*g]);
    f32x4 a2[2][4];
#pragma unroll
    for (int m2 = 0; m2 < 2; ++m2)
#pragma unroll
        for (int ct = 0; ct < 4; ++ct) a2[m2][ct] = vzero;
#pragma unroll
    for (int ct = 0; ct < 4; ++ct)
#pragma unroll
        for (int ks = 0; ks < 4; ++ks) {
            Frag2 bf; bf.u2 = BF2[(8 + ks*4 + ct)*64 + l];
#pragma unroll
            for (int m2 = 0; m2 < 2; ++m2)
                a2[m2][ct] = mfma16(ah[m2][ks].f, bf.f, a2[m2][ct]);
        }
    __syncthreads();                                   // B6: h1 dead
#pragma unroll
    for (int m2 = 0; m2 < 2; ++m2)
#pragma unroll
        for (int q = 0; q < 4; ++q) {
            int r = m2*16 + g*4 + q;
#pragma unroll
            for (int t2 = 0; t2 < 4; ++t2)
                hb[r*72 + cl + 16*t2] = f16bits(fmaxf(a2[m2][t2][q] + b2c[t2], 0.0f));
        }
    __syncthreads();                                   // B7: hb(h2) ready

    // ---- enc3 ----
#pragma unroll
    for (int m2 = 0; m2 < 2; ++m2)
#pragma unroll
        for (int ks = 0; ks < 4; ++ks)
            ah[m2][ks].uh = *reinterpret_cast<const u16x4v*>(&hb[(m2*16 + cl)*72 + ks*16 + 4*g]);
    __syncthreads();                                   // B8: h2 dead -> at(latent)
#pragma unroll
    for (int m2 = 0; m2 < 2; ++m2) {
        f32x4 a3 = vzero;
#pragma unroll
        for (int ks = 0; ks < 4; ++ks) {
            Frag2 bf; bf.u2 = BF2[(24 + ks)*64 + l];
            a3 = mfma16(ah[m2][ks].f, bf.f, a3);
        }
#pragma unroll
        for (int q = 0; q < 4; ++q) {
            float lv = a3[q] + b3c;
            int r = m2*16 + g*4 + q;
            if (cl < 14)
                out[(long long)8 * N + (rowbase + r) * 14 + cl] = lv;
            float pv = __shfl_xor(lv, 1);
            if ((cl & 1) == 0)
                at[r*36 + (cl >> 1)] = packrtz(lv, pv);
        }
    }
    __syncthreads();                                   // B9: at(latent) ready

    // ---- dec1 ----
    Frag2 aD[2];
#pragma unroll
    for (int m2 = 0; m2 < 2; ++m2)
        aD[m2].u2 = *reinterpret_cast<const u32x2v*>(&at[(m2*16 + cl)*36 + 2*g]);
    __syncthreads();                                   // B10: latent dead -> hb
    f32x4 ad[2][4];
#pragma unroll
    for (int m2 = 0; m2 < 2; ++m2)
#pragma unroll
        for (int ct = 0; ct < 4; ++ct) ad[m2][ct] = vzero;
#pragma unroll
    for (int ct = 0; ct < 4; ++ct) {
        Frag2 bf; bf.u2 = BF2[(28 + ct)*64 + l];
#pragma unroll
        for (int m2 = 0; m2 < 2; ++m2)
            ad[m2][ct] = mfma16(aD[m2].f, bf.f, ad[m2][ct]);
    }
#pragma unroll
    for (int m2 = 0; m2 < 2; ++m2)
#pragma unroll
        for (int q = 0; q < 4; ++q) {
            int r = m2*16 + g*4 + q;
#pragma unroll
            for (int t2 = 0; t2 < 4; ++t2)
                hb[r*72 + cl + 16*t2] = f16bits(fmaxf(ad[m2][t2][q] + bd1c[t2], 0.0f));
        }
    __syncthreads();                                   // B11: hb(d1) ready

    // ---- dec2 ----
#pragma unroll
    for (int m2 = 0; m2 < 2; ++m2)
#pragma unroll
        for (int ks = 0; ks < 4; ++ks)
            ah[m2][ks].uh = *reinterpret_cast<const u16x4v*>(&hb[(m2*16 + cl)*72 + ks*16 + 4*g]);
#pragma unroll
    for (int m2 = 0; m2 < 2; ++m2) {
        f32x4 a5 = vzero;
#pragma unroll
        for (int ks = 0; ks < 4; ++ks) {
            Frag2 bf; bf.u2 = BF2[(32 + ks)*64 + l];
            a5 = mfma16(ah[m2][ks].f, bf.f, a5);
        }
#pragma unroll
        for (int q = 0; q < 4; ++q) {
            if (cl < 8)
                out[(rowbase + m2*16 + g*4 + q) * 8 + cl] = ftanh(a5[q] + bd2c);
        }
    }
}

extern "C" void kernel_launch(void* const* d_in, const int* in_sizes, int n_in,
                              void* d_out, int out_size, void* d_ws, size_t ws_size,
                              hipStream_t stream)
{
    const float* state = (const float*)d_in[0];
    const float* W1   = (const float*)d_in[1];
    const float* b1   = (const float*)d_in[2];
    const float* lng  = (const float*)d_in[3];
    const float* lnb  = (const float*)d_in[4];
    const float* W2   = (const float*)d_in[5];
    const float* b2   = (const float*)d_in[6];
    const float* W3   = (const float*)d_in[7];
    const float* b3   = (const float*)d_in[8];
    const float* Wd1  = (const float*)d_in[9];
    const float* bd1  = (const float*)d_in[10];
    const float* Wd2  = (const float*)d_in[11];
    const float* bd2  = (const float*)d_in[12];
    const float* Wm   = (const float*)d_in[13];
    const float* bm   = (const float*)d_in[14];
    const float* Wh   = (const float*)d_in[15];
    const float* bh   = (const float*)d_in[16];
    const float* Wc   = (const float*)d_in[17];
    const float* bc   = (const float*)d_in[18];
    const float* psm  = (const float*)d_in[19];
    const float* psh  = (const float*)d_in[20];
    const float* psc  = (const float*)d_in[21];

    unsigned* pw = (unsigned*)d_ws;

    hipLaunchKernelGGL(pack_bfrags, dim3((NFRAG*64 + 255)/256), dim3(256), 0, stream,
                       W1, W2, W3, Wd1, Wd2, Wm, Wh, Wc, pw);

    const int N = in_sizes[0] / SD;              // 1048576
    hipLaunchKernelGGL(statenet_mfma6, dim3(N / 128), dim3(256), 0, stream,
                       state, pw, b1, lng, lnb, b2, b3, bd1, bd2,
                       bm, bh, bc, psm, psh, psc,
                       (float*)d_out, N);
}

// Round 20
// 123.027 us; speedup vs baseline: 1.1148x; 1.0452x over previous
//
#include <hip/hip_runtime.h>

static constexpr int SD = 21, HD = 64, LT = 14;
static constexpr int NFRAG = 40;     // 36 MLP frags + 4 head frags (fid 36-39)

typedef _Float16       f16x4  __attribute__((ext_vector_type(4)));
typedef float          f32x4  __attribute__((ext_vector_type(4)));
typedef unsigned       u32x2v __attribute__((ext_vector_type(2)));
typedef unsigned short u16x4v __attribute__((ext_vector_type(4)));
typedef __fp16         pk2    __attribute__((ext_vector_type(2)));

__device__ __forceinline__ float frcp(float x){ return __builtin_amdgcn_rcpf(x); }
__device__ __forceinline__ float frsq(float x){ return __builtin_amdgcn_rsqf(x); }

// wave-local LDS ordering fence: drain DS queue + block compiler motion.
// (all LDS buffers are wave-private -> no inter-wave rendezvous needed; rule #18:
//  follow inline-asm waitcnt with sched_barrier(0) so MFMA/VALU can't hoist past)
__device__ __forceinline__ void wave_fence(){
    asm volatile("s_waitcnt lgkmcnt(0)" ::: "memory");
    __builtin_amdgcn_sched_barrier(0);
}

__device__ __forceinline__ unsigned packrtz(float a, float b){
    pk2 h = __builtin_amdgcn_cvt_pkrtz(a, b);
    union { pk2 h; unsigned u; } u; u.h = h; return u.u;
}
__device__ __forceinline__ unsigned short f16bits(float v){
    _Float16 h = (_Float16)v;
    union { _Float16 h; unsigned short s; } u; u.h = h; return u.s;
}
__device__ __forceinline__ float ftanh(float x){
    x = fminf(15.0f, fmaxf(-15.0f, x));
    float e = __expf(2.0f * x);
    return (e - 1.0f) * frcp(e + 1.0f);
}
template<int NN>
__device__ __forceinline__ void softmax_scale(float (&v)[NN], float gate){
    float mx = v[0];
#pragma unroll
    for (int j = 1; j < NN; ++j) mx = fmaxf(mx, v[j]);
    float s = 0.0f;
#pragma unroll
    for (int j = 0; j < NN; ++j){ v[j] = __expf(v[j] - mx); s += v[j]; }
    float r = frcp(s) * gate;
#pragma unroll
    for (int j = 0; j < NN; ++j) v[j] *= r;
}

union Frag2 { u32x2v u2; unsigned u[2]; f16x4 f; };
union FragH { u16x4v uh; f16x4 f; };

__device__ __forceinline__ f32x4 mfma16(f16x4 a, f16x4 b, f32x4 c){
    return __builtin_amdgcn_mfma_f32_16x16x16f16(a, b, c, 0, 0, 0);
}

// heads concat weight: col j of [Wm | Wh | Wc] (21 x 23)
__device__ __forceinline__ float headsW(const float* Wm, const float* Wh,
                                        const float* Wc, int k, int j){
    if (j < 13) return Wm[k*13 + j];
    if (j < 19) return Wh[k*6 + (j - 13)];
    if (j < 23) return Wc[k*4 + (j - 19)];
    return 0.0f;
}

// ---- B-fragment pack: layout col=l&15, k=4*(l>>4)+r (HW-verified R12/R13/R14) ----
// fid: 0-7 enc1 | 8-23 enc2 | 24-27 enc3 | 28-31 dec1 | 32-35 dec2 | 36-39 heads
__global__ void pack_bfrags(const float* __restrict__ W1, const float* __restrict__ W2,
                            const float* __restrict__ W3, const float* __restrict__ Wd1,
                            const float* __restrict__ Wd2,
                            const float* __restrict__ Wm, const float* __restrict__ Wh,
                            const float* __restrict__ Wc, unsigned* __restrict__ ws)
{
    int t = blockIdx.x * blockDim.x + threadIdx.x;
    if (t >= NFRAG * 64) return;
    int fid = t >> 6, lane = t & 63;
    int g = lane >> 4, c = lane & 15;

    if (fid >= 36) {                 // heads: [Wm|Wh|Wc] 21x23, K pad 32, col pad 32
        int e = fid - 36, ks16 = e >> 1, ct = e & 1;
        int col = ct*16 + c;
#pragma unroll
        for (int j = 0; j < 2; ++j) {
            int k0 = ks16*16 + g*4 + 2*j;
            float a = (k0     < SD && col < 23) ? headsW(Wm, Wh, Wc, k0,   col) : 0.0f;
            float b = (k0 + 1 < SD && col < 23) ? headsW(Wm, Wh, Wc, k0+1, col) : 0.0f;
            ws[fid*128 + lane*2 + j] = packrtz(a, b);
        }
        return;
    }

    const float* W; int ks16, ct, K, Ncol, ld;
    if (fid < 8)       { W = W1;  ks16 = fid >> 2;    ct = fid & 3;  K = 21; Ncol = 64; ld = 64; }
    else if (fid < 24) { int e = fid - 8;
                         W = W2;  ks16 = e >> 2;      ct = e & 3;    K = 64; Ncol = 64; ld = 64; }
    else if (fid < 28) { W = W3;  ks16 = fid - 24;    ct = 0;        K = 64; Ncol = 14; ld = 14; }
    else if (fid < 32) { W = Wd1; ks16 = 0;           ct = fid - 28; K = 14; Ncol = 64; ld = 64; }
    else               { W = Wd2; ks16 = fid - 32;    ct = 0;        K = 64; Ncol = 8;  ld = 8;  }
    int col = ct*16 + c;
#pragma unroll
    for (int j = 0; j < 2; ++j) {
        int k0 = ks16*16 + g*4 + 2*j;
        float a = (k0     < K && col < Ncol) ? W[k0*ld + col]     : 0.0f;
        float b = (k0 + 1 < K && col < Ncol) ? W[(k0+1)*ld + col] : 0.0f;
        ws[fid*128 + lane*2 + j] = packrtz(a, b);
    }
}

__global__ __launch_bounds__(256) void statenet_mfma7(
    const float* __restrict__ state,
    const unsigned* __restrict__ pw,
    const float* __restrict__ b1,
    const float* __restrict__ lng, const float* __restrict__ lnb,
    const float* __restrict__ b2,  const float* __restrict__ b3,
    const float* __restrict__ bd1, const float* __restrict__ bd2,
    const float* __restrict__ bm,  const float* __restrict__ bh,
    const float* __restrict__ bc,
    const float* __restrict__ psm, const float* __restrict__ psh,
    const float* __restrict__ psc,
    float* __restrict__ out, int N)
{
    // R17-verified overlay: at[32][36] u32  <->  hb[32][72] f16 per wave.
    // ALL buffers are wave-private (indexed by w) -> ordering via wave_fence(),
    // no __syncthreads: waves free-run, no inter-wave rendezvous or vmcnt drain.
    __shared__ __align__(16) unsigned s_buf[4*1152];   // 18432 B
    __shared__ __align__(16) float    s_lg[4*832];     // logits [32][26] f32/wave

    const int tid = threadIdx.x;
    const int w  = tid >> 6, l = tid & 63;
    const int cl = l & 15,  g = l >> 4;
    const long long rowbase = (long long)blockIdx.x * 128 + w * 32;

    unsigned*       at  = s_buf + w * 1152;
    unsigned short* hb  = reinterpret_cast<unsigned short*>(s_buf) + w * 2304;
    float*          slg = s_lg + w * 832;

    // per-lane head-bias for logit columns (ct0 col=cl, ct1 col=16+cl)
    const float bc0 = (cl < 13) ? bm[cl] : bh[cl - 13];
    const float bc1 = (cl < 3) ? bh[cl + 3] : ((cl < 7) ? bc[cl - 3] : 0.0f);

    // ============ T1-A: load + normalize + stage ns (lanes 0..31) ============
    float ns[SD];
    if (l < 32) {
        const long long row = rowbase + l;
        {
            const float* p = state + row * SD;
#pragma unroll
            for (int k = 0; k < SD; ++k) ns[k] = p[k];
        }
        ns[0]  *= (1.0f / 3.0f);
        ns[1]  *= (1.0f / 3.0f);
        ns[17] *= 0.5f;
        ns[18] *= 0.25f;
        ns[19]  = fminf(fmaxf(ns[19], 0.0f), 2.0f) * 0.5f;

        const int base = l * 36;
#pragma unroll
        for (int kk = 0; kk < 10; ++kk) at[base + kk] = packrtz(ns[2*kk], ns[2*kk+1]);
        at[base + 10] = packrtz(ns[20], 0.0f);
#pragma unroll
        for (int kk = 11; kk < 16; ++kk) at[base + kk] = 0u;
    }
    wave_fence();                                      // F1: at(ns) ready

    // ============ heads MFMA: logits = ns @ [Wm|Wh|Wc] ============
    const u32x2v* BF2 = reinterpret_cast<const u32x2v*>(pw);
    const f32x4 vzero = {0.0f, 0.0f, 0.0f, 0.0f};
    {
        Frag2 aN[2][2];
#pragma unroll
        for (int m2 = 0; m2 < 2; ++m2)
#pragma unroll
            for (int ks = 0; ks < 2; ++ks)
                aN[m2][ks].u2 = *reinterpret_cast<const u32x2v*>(&at[(m2*16 + cl)*36 + ks*8 + 2*g]);
        f32x4 hl[2][2];
#pragma unroll
        for (int m2 = 0; m2 < 2; ++m2)
#pragma unroll
            for (int ct = 0; ct < 2; ++ct) hl[m2][ct] = vzero;
#pragma unroll
        for (int ct = 0; ct < 2; ++ct)
#pragma unroll
            for (int ks = 0; ks < 2; ++ks) {
                Frag2 bf; bf.u2 = BF2[(36 + ks*2 + ct)*64 + l];
#pragma unroll
                for (int m2 = 0; m2 < 2; ++m2)
                    hl[m2][ct] = mfma16(aN[m2][ks].f, bf.f, hl[m2][ct]);
            }
#pragma unroll
        for (int m2 = 0; m2 < 2; ++m2)
#pragma unroll
            for (int q = 0; q < 4; ++q) {
                int r = m2*16 + g*4 + q;
                slg[r*26 + cl] = hl[m2][0][q] + bc0;
                if (cl < 8) slg[r*26 + 16 + cl] = hl[m2][1][q] + bc1;
            }
    }
    wave_fence();                                      // F2: logits ready

    // ============ T1-B: softmax + head stores + attended (lanes 0..31) ============
    if (l < 32) {
        const long long row = rowbase + l;
        float lg[24];
#pragma unroll
        for (int i = 0; i < 12; ++i) {
            float2 v = *reinterpret_cast<const float2*>(&slg[l*26 + 2*i]);
            lg[2*i] = v.x; lg[2*i+1] = v.y;
        }
        float m[13], hv[6], cv[4];
#pragma unroll
        for (int j = 0; j < 13; ++j) m[j]  = lg[j];
#pragma unroll
        for (int j = 0; j < 6;  ++j) hv[j] = lg[13 + j];
#pragma unroll
        for (int j = 0; j < 4;  ++j) cv[j] = lg[19 + j];

        const float gm = 2.0f * frcp(1.0f + __expf(-psm[0]));
        const float gh = 2.0f * frcp(1.0f + __expf(-psh[0]));
        const float gc = 2.0f * frcp(1.0f + __expf(-psc[0]));
        softmax_scale<13>(m,  gm);
        softmax_scale<6 >(hv, gh);
        softmax_scale<4 >(cv, gc);

        {
            float* pm = out + (long long)22 * N + row * 13;
#pragma unroll
            for (int j = 0; j < 13; ++j) pm[j] = m[j];
            float* ph = out + (long long)35 * N + row * 6;
#pragma unroll
            for (int j = 0; j < 3; ++j)
                reinterpret_cast<float2*>(ph)[j] = make_float2(hv[2*j], hv[2*j+1]);
            float* pc = out + (long long)41 * N + row * 4;
            reinterpret_cast<float4*>(pc)[0] = make_float4(cv[0], cv[1], cv[2], cv[3]);
        }

        constexpr int EIDX[SD] = {0,1,2,3,4,4,5,5,5,6,6,6,7,7,8,9,9,10,10,11,12};
        float atv[SD];
#pragma unroll
        for (int k = 0; k < SD; ++k) atv[k] = ns[k] * m[EIDX[k]];
        const int base = l * 36;
#pragma unroll
        for (int kk = 0; kk < 10; ++kk) at[base + kk] = packrtz(atv[2*kk], atv[2*kk+1]);
        at[base + 10] = packrtz(atv[20], 0.0f);
        // pads 11..15 still zero from T1-A
    }
    wave_fence();                                      // F3: at(attended) ready

    // ============ MFMA chain (R17-verified math, fences instead of barriers) ============
    float b1c[4], b2c[4], bd1c[4], lgc[4], lbc[4];
#pragma unroll
    for (int t2 = 0; t2 < 4; ++t2) {
        int c2 = cl + 16*t2;
        b1c[t2] = b1[c2];  b2c[t2] = b2[c2];  bd1c[t2] = bd1[c2];
        lgc[t2] = lng[c2]; lbc[t2] = lnb[c2];
    }
    const float b3c  = (cl < 14) ? b3[cl]  : 0.0f;
    const float bd2c = (cl < 8)  ? bd2[cl] : 0.0f;

    // ---- enc1: read at -> regs ----
    Frag2 aA[2][2];
#pragma unroll
    for (int m2 = 0; m2 < 2; ++m2)
#pragma unroll
        for (int ks = 0; ks < 2; ++ks)
            aA[m2][ks].u2 = *reinterpret_cast<const u32x2v*>(&at[(m2*16 + cl)*36 + ks*8 + 2*g]);
    wave_fence();                                      // F4: at dead -> hb

    f32x4 acc[2][4];
#pragma unroll
    for (int m2 = 0; m2 < 2; ++m2)
#pragma unroll
        for (int ct = 0; ct < 4; ++ct) acc[m2][ct] = vzero;
#pragma unroll
    for (int ct = 0; ct < 4; ++ct)
#pragma unroll
        for (int ks = 0; ks < 2; ++ks) {
            Frag2 bf; bf.u2 = BF2[(ks*4 + ct)*64 + l];
#pragma unroll
            for (int m2 = 0; m2 < 2; ++m2)
                acc[m2][ct] = mfma16(aA[m2][ks].f, bf.f, acc[m2][ct]);
        }
#pragma unroll
    for (int m2 = 0; m2 < 2; ++m2) {
        float s[4], ss[4];
#pragma unroll
        for (int q = 0; q < 4; ++q) {
            float v0 = acc[m2][0][q] + b1c[0], v1 = acc[m2][1][q] + b1c[1];
            float v2 = acc[m2][2][q] + b1c[2], v3 = acc[m2][3][q] + b1c[3];
            acc[m2][0][q] = v0; acc[m2][1][q] = v1; acc[m2][2][q] = v2; acc[m2][3][q] = v3;
            s[q]  = v0 + v1 + v2 + v3;
            ss[q] = v0*v0 + v1*v1 + v2*v2 + v3*v3;
        }
#pragma unroll
        for (int q = 0; q < 4; ++q) {
#pragma unroll
            for (int d = 1; d < 16; d <<= 1) {
                s[q]  += __shfl_xor(s[q],  d, 16);
                ss[q] += __shfl_xor(ss[q], d, 16);
            }
        }
#pragma unroll
        for (int q = 0; q < 4; ++q) {
            float mu   = s[q] * (1.0f/64.0f);
            float var  = ss[q] * (1.0f/64.0f) - mu*mu;
            float istd = frsq(var + 1e-5f);
            int r = m2*16 + g*4 + q;
#pragma unroll
            for (int t2 = 0; t2 < 4; ++t2) {
                float v = ftanh(fmaf((acc[m2][t2][q] - mu) * istd, lgc[t2], lbc[t2]));
                hb[r*72 + cl + 16*t2] = f16bits(v);
            }
        }
    }
    wave_fence();                                      // F5: hb(h1) ready

    // ---- enc2 ----
    FragH ah[2][4];
#pragma unroll
    for (int m2 = 0; m2 < 2; ++m2)
#pragma unroll
        for (int ks = 0; ks < 4; ++ks)
            ah[m2][ks].uh = *reinterpret_cast<const u16x4v*>(&hb[(m2*16 + cl)*72 + ks*16 + 4*g]);
    f32x4 a2[2][4];
#pragma unroll
    for (int m2 = 0; m2 < 2; ++m2)
#pragma unroll
        for (int ct = 0; ct < 4; ++ct) a2[m2][ct] = vzero;
#pragma unroll
    for (int ct = 0; ct < 4; ++ct)
#pragma unroll
        for (int ks = 0; ks < 4; ++ks) {
            Frag2 bf; bf.u2 = BF2[(8 + ks*4 + ct)*64 + l];
#pragma unroll
            for (int m2 = 0; m2 < 2; ++m2)
                a2[m2][ct] = mfma16(ah[m2][ks].f, bf.f, a2[m2][ct]);
        }
    wave_fence();                                      // F6: h1 reads done
#pragma unroll
    for (int m2 = 0; m2 < 2; ++m2)
#pragma unroll
        for (int q = 0; q < 4; ++q) {
            int r = m2*16 + g*4 + q;
#pragma unroll
            for (int t2 = 0; t2 < 4; ++t2)
                hb[r*72 + cl + 16*t2] = f16bits(fmaxf(a2[m2][t2][q] + b2c[t2], 0.0f));
        }
    wave_fence();                                      // F7: hb(h2) ready

    // ---- enc3 ----
#pragma unroll
    for (int m2 = 0; m2 < 2; ++m2)
#pragma unroll
        for (int ks = 0; ks < 4; ++ks)
            ah[m2][ks].uh = *reinterpret_cast<const u16x4v*>(&hb[(m2*16 + cl)*72 + ks*16 + 4*g]);
    wave_fence();                                      // F8: h2 dead -> at(latent)
#pragma unroll
    for (int m2 = 0; m2 < 2; ++m2) {
        f32x4 a3 = vzero;
#pragma unroll
        for (int ks = 0; ks < 4; ++ks) {
            Frag2 bf; bf.u2 = BF2[(24 + ks)*64 + l];
            a3 = mfma16(ah[m2][ks].f, bf.f, a3);
        }
#pragma unroll
        for (int q = 0; q < 4; ++q) {
            float lv = a3[q] + b3c;
            int r = m2*16 + g*4 + q;
            if (cl < 14)
                out[(long long)8 * N + (rowbase + r) * 14 + cl] = lv;
            float pv = __shfl_xor(lv, 1);
            if ((cl & 1) == 0)
                at[r*36 + (cl >> 1)] = packrtz(lv, pv);
        }
    }
    wave_fence();                                      // F9: at(latent) ready

    // ---- dec1 ----
    Frag2 aD[2];
#pragma unroll
    for (int m2 = 0; m2 < 2; ++m2)
        aD[m2].u2 = *reinterpret_cast<const u32x2v*>(&at[(m2*16 + cl)*36 + 2*g]);
    wave_fence();                                      // F10: latent dead -> hb
    f32x4 ad[2][4];
#pragma unroll
    for (int m2 = 0; m2 < 2; ++m2)
#pragma unroll
        for (int ct = 0; ct < 4; ++ct) ad[m2][ct] = vzero;
#pragma unroll
    for (int ct = 0; ct < 4; ++ct) {
        Frag2 bf; bf.u2 = BF2[(28 + ct)*64 + l];
#pragma unroll
        for (int m2 = 0; m2 < 2; ++m2)
            ad[m2][ct] = mfma16(aD[m2].f, bf.f, ad[m2][ct]);
    }
#pragma unroll
    for (int m2 = 0; m2 < 2; ++m2)
#pragma unroll
        for (int q = 0; q < 4; ++q) {
            int r = m2*16 + g*4 + q;
#pragma unroll
            for (int t2 = 0; t2 < 4; ++t2)
                hb[r*72 + cl + 16*t2] = f16bits(fmaxf(ad[m2][t2][q] + bd1c[t2], 0.0f));
        }
    wave_fence();                                      // F11: hb(d1) ready

    // ---- dec2 ----
#pragma unroll
    for (int m2 = 0; m2 < 2; ++m2)
#pragma unroll
        for (int ks = 0; ks < 4; ++ks)
            ah[m2][ks].uh = *reinterpret_cast<const u16x4v*>(&hb[(m2*16 + cl)*72 + ks*16 + 4*g]);
#pragma unroll
    for (int m2 = 0; m2 < 2; ++m2) {
        f32x4 a5 = vzero;
#pragma unroll
        for (int ks = 0; ks < 4; ++ks) {
            Frag2 bf; bf.u2 = BF2[(32 + ks)*64 + l];
            a5 = mfma16(ah[m2][ks].f, bf.f, a5);
        }
#pragma unroll
        for (int q = 0; q < 4; ++q) {
            if (cl < 8)
                out[(rowbase + m2*16 + g*4 + q) * 8 + cl] = ftanh(a5[q] + bd2c);
        }
    }
}

extern "C" void kernel_launch(void* const* d_in, const int* in_sizes, int n_in,
                              void* d_out, int out_size, void* d_ws, size_t ws_size,
                              hipStream_t stream)
{
    const float* state = (const float*)d_in[0];
    const float* W1   = (const float*)d_in[1];
    const float* b1   = (const float*)d_in[2];
    const float* lng  = (const float*)d_in[3];
    const float* lnb  = (const float*)d_in[4];
    const float* W2   = (const float*)d_in[5];
    const float* b2   = (const float*)d_in[6];
    const float* W3   = (const float*)d_in[7];
    const float* b3   = (const float*)d_in[8];
    const float* Wd1  = (const float*)d_in[9];
    const float* bd1  = (const float*)d_in[10];
    const float* Wd2  = (const float*)d_in[11];
    const float* bd2  = (const float*)d_in[12];
    const float* Wm   = (const float*)d_in[13];
    const float* bm   = (const float*)d_in[14];
    const float* Wh   = (const float*)d_in[15];
    const float* bh   = (const float*)d_in[16];
    const float* Wc   = (const float*)d_in[17];
    const float* bc   = (const float*)d_in[18];
    const float* psm  = (const float*)d_in[19];
    const float* psh  = (const float*)d_in[20];
    const float* psc  = (const float*)d_in[21];

    unsigned* pw = (unsigned*)d_ws;

    hipLaunchKernelGGL(pack_bfrags, dim3((NFRAG*64 + 255)/256), dim3(256), 0, stream,
                       W1, W2, W3, Wd1, Wd2, Wm, Wh, Wc, pw);

    const int N = in_sizes[0] / SD;              // 1048576
    hipLaunchKernelGGL(statenet_mfma7, dim3(N / 128), dim3(256), 0, stream,
                       state, pw, b1, lng, lnb, b2, b3, bd1, bd2,
                       bm, bh, bc, psm, psh, psc,
                       (float*)d_out, N);
}